// Round 3
// baseline (673.203 us; speedup 1.0000x reference)
//
#include <hip/hip_runtime.h>
#include <hip/hip_bf16.h>
#include <math.h>

// Problem dims (fixed by reference)
#define T_TOK 8192          // B*S tokens
#define DIM   2048          // D
#define NE    8             // experts
#define MDIM  1024          // intermediate
#define TK    16384         // T*K token copies
#define CAP   (TK + 256)    // slack rows so 256-row edge tiles can over-read safely
#define MAXT  72            // sum_e ceil(cnt_e/256) <= 64 + 8

typedef __attribute__((ext_vector_type(8))) short bf16x8;
typedef __attribute__((ext_vector_type(4))) float f32x4;
typedef __attribute__((ext_vector_type(16))) float f32x16;

typedef __attribute__((address_space(3))) unsigned char* lds_ptr_t;
typedef const __attribute__((address_space(1))) unsigned char* glb_ptr_t;

__device__ __forceinline__ unsigned short f2bf(float f) {
  union { float f; unsigned u; } v; v.f = f;
  unsigned r = v.u + 0x7fffu + ((v.u >> 16) & 1u);  // round-to-nearest-even
  return (unsigned short)(r >> 16);
}

__device__ __forceinline__ void gload_lds16(const void* g, void* l) {
  // each lane loads 16B from its own global addr; lands at lds_base + lane*16
  __builtin_amdgcn_global_load_lds((glb_ptr_t)g, (lds_ptr_t)l, 16, 0, 0);
}

#define VM_FENCE(n) asm volatile("s_waitcnt vmcnt(" #n ")" ::: "memory")
#define BARRIER() __builtin_amdgcn_s_barrier()

// Stage one 128x64 bf16 unit (16 KB) into LDS, linear dest, INVERSE-swizzled
// global source so that a swizzled ds_read (byte ^= (row&7)<<4) sees the right
// data (rule #21: both-sides-or-neither). 512 threads x 2 insts x 16B = 16 KB.
// Per wave this is exactly 2 vmcnt increments.
__device__ __forceinline__ void stage_unit(const unsigned short* __restrict__ src,
                                           int ld, unsigned char* lds, int tid) {
#pragma unroll
  for (int j = 0; j < 2; j++) {
    int idx = j * 512 + tid;
    int row = idx >> 3;                       // 0..127
    int gslot = (idx & 7) ^ (row & 7);        // inverse swizzle on source
    gload_lds16(src + (size_t)row * ld + gslot * 8, lds + ((idx & ~63) << 4));
  }
}

// Swizzled LDS fragment read: row stride 128B, XOR bits 4-6 with row&7.
__device__ __forceinline__ bf16x8 ldsfrag(const unsigned char* base, int row, int kb) {
  return *(const bf16x8*)(base + row * 128 + (kb ^ ((row & 7) << 4)));
}

// ---------------- router: fp64 logits, top-2, softmax weights ----------------
__global__ __launch_bounds__(256) void router_kernel(
    const float* __restrict__ x, const float* __restrict__ wg,
    int* __restrict__ tok_eid, float* __restrict__ tok_w) {
  __shared__ float wgT[NE][1024];  // 32 KB, one D-half at a time
  int tid = threadIdx.x;
  int wave = tid >> 6, lane = tid & 63;
  int t0 = blockIdx.x * 16 + wave * 4;  // 512 blocks x 4 waves x 4 tokens = 8192

  double acc[4][NE];
#pragma unroll
  for (int tt = 0; tt < 4; tt++)
#pragma unroll
    for (int e = 0; e < NE; e++) acc[tt][e] = 0.0;

  for (int p = 0; p < 2; p++) {
    __syncthreads();
#pragma unroll
    for (int j = tid; j < 2048; j += 256) {
      float4 v = ((const float4*)wg)[p * 2048 + j];
      int d = j >> 1, h = (j & 1) * 4;
      wgT[h + 0][d] = v.x;
      wgT[h + 1][d] = v.y;
      wgT[h + 2][d] = v.z;
      wgT[h + 3][d] = v.w;
    }
    __syncthreads();
#pragma unroll
    for (int it = 0; it < 4; it++) {
      int dd = it * 256 + lane * 4;
      int gd = p * 1024 + dd;
      float4 wf[NE];
#pragma unroll
      for (int e = 0; e < NE; e++) wf[e] = *(const float4*)&wgT[e][dd];
#pragma unroll
      for (int tt = 0; tt < 4; tt++) {
        float4 xv = *(const float4*)(x + (size_t)(t0 + tt) * DIM + gd);
#pragma unroll
        for (int e = 0; e < NE; e++) {
          acc[tt][e] += (double)xv.x * (double)wf[e].x;
          acc[tt][e] += (double)xv.y * (double)wf[e].y;
          acc[tt][e] += (double)xv.z * (double)wf[e].z;
          acc[tt][e] += (double)xv.w * (double)wf[e].w;
        }
      }
    }
  }
#pragma unroll
  for (int tt = 0; tt < 4; tt++)
#pragma unroll
    for (int e = 0; e < NE; e++) {
      double v = acc[tt][e];
#pragma unroll
      for (int off = 32; off > 0; off >>= 1) v += __shfl_down(v, off, 64);
      acc[tt][e] = v;
    }
  if (lane == 0) {
#pragma unroll
    for (int tt = 0; tt < 4; tt++) {
      int t = t0 + tt;
      int b0 = 0; double l0 = acc[tt][0];
#pragma unroll
      for (int e = 1; e < NE; e++) { if (acc[tt][e] > l0) { l0 = acc[tt][e]; b0 = e; } }
      int b1 = -1; double l1 = -1.0e300;
#pragma unroll
      for (int e = 0; e < NE; e++) { if (e != b0 && acc[tt][e] > l1) { l1 = acc[tt][e]; b1 = e; } }
      double w0 = 1.0 / (1.0 + exp(l1 - l0));
      tok_eid[2 * t]     = b0;
      tok_eid[2 * t + 1] = b1;
      tok_w[2 * t]     = (float)w0;
      tok_w[2 * t + 1] = (float)(1.0 - w0);
    }
  }
}

// ---------------- plan: counting sort of tok_eid -> offsets/tstart/tok_slot --
__global__ __launch_bounds__(256) void plan_kernel(
    const int* __restrict__ tok_eid, int* __restrict__ offsets,
    int* __restrict__ tstart, int* __restrict__ tok_slot) {
  __shared__ int cnt[256][NE];
  __shared__ int pre[256][NE];
  __shared__ int tot[NE];
  __shared__ int off_sh[NE + 1];
  int th = threadIdx.x;
  int c[NE];
#pragma unroll
  for (int k = 0; k < NE; k++) c[k] = 0;
  for (int i = 0; i < TK / 256; i++) {
    int e = tok_eid[i * 256 + th];
#pragma unroll
    for (int k = 0; k < NE; k++) c[k] += (e == k) ? 1 : 0;
  }
#pragma unroll
  for (int k = 0; k < NE; k++) cnt[th][k] = c[k];
  __syncthreads();
  if (th < NE) {
    int run = 0;
#pragma unroll 4
    for (int i = 0; i < 256; i++) { pre[i][th] = run; run += cnt[i][th]; }
    tot[th] = run;
  }
  __syncthreads();
  if (th == 0) {
    int s = 0, ts = 0;
    for (int e = 0; e < NE; e++) {
      off_sh[e] = s; offsets[e] = s; s += tot[e];
      tstart[e] = ts; ts += (tot[e] + 255) / 256;   // 256-row tiles
    }
    offsets[NE] = s; off_sh[NE] = s; tstart[NE] = ts;
  }
  __syncthreads();
  int b[NE];
#pragma unroll
  for (int k = 0; k < NE; k++) b[k] = off_sh[k] + pre[th][k];
  for (int i = 0; i < TK / 256; i++) {
    int idx = i * 256 + th;
    int e = tok_eid[idx];
    int slot = 0;
#pragma unroll
    for (int k = 0; k < NE; k++) {
      slot = (e == k) ? b[k] : slot;
      b[k] += (e == k) ? 1 : 0;
    }
    tok_slot[idx] = slot;
  }
}

// ---------------- dispatch: gather x -> sorted_x (bf16), atomic-free --------
__global__ __launch_bounds__(256) void dispatch_kernel(
    const float* __restrict__ x, const int* __restrict__ tok_slot,
    unsigned short* __restrict__ sorted_x) {
  int t = blockIdx.x;
  size_t s0 = (size_t)tok_slot[2 * t] * DIM;
  size_t s1 = (size_t)tok_slot[2 * t + 1] * DIM;
  const float4* xr = (const float4*)(x + (size_t)t * DIM);
#pragma unroll
  for (int i = threadIdx.x; i < DIM / 4; i += 256) {
    float4 v = xr[i];
    ushort4 b;
    b.x = f2bf(v.x); b.y = f2bf(v.y); b.z = f2bf(v.z); b.w = f2bf(v.w);
    *(ushort4*)(sorted_x + s0 + (size_t)i * 4) = b;
    *(ushort4*)(sorted_x + s1 + (size_t)i * 4) = b;
  }
}

// ---------------- weight cast + transpose: f32 [R][C] -> bf16 [C][R] --------
__global__ __launch_bounds__(256) void transpose_cast_kernel(
    const float* __restrict__ in, unsigned short* __restrict__ out, int R, int C) {
  __shared__ unsigned short tile[32][33];
  int e = blockIdx.z;
  const float* inp = in + (size_t)e * R * C;
  unsigned short* outp = out + (size_t)e * R * C;
  int c0 = blockIdx.x * 32, r0 = blockIdx.y * 32;
  int tx = threadIdx.x & 31, ty = threadIdx.x >> 5;
#pragma unroll
  for (int i = 0; i < 32; i += 8)
    tile[ty + i][tx] = f2bf(inp[(size_t)(r0 + ty + i) * C + (c0 + tx)]);
  __syncthreads();
#pragma unroll
  for (int i = 0; i < 32; i += 8)
    outp[(size_t)(c0 + ty + i) * R + (r0 + tx)] = tile[tx][ty + i];
}

// ---------------- GEMM12: inter = silu(A@wi0) * (A@wi1) --------------------
// 3-phase K-loop, 32x32x16 MFMA, deep prefetch: BM=256, BK=64, 512 thr/8 waves,
// 128 KiB dbuf LDS {A0|A1|B0|B1} x2 (16 KB units, 128x64 bf16 each).
// ALL 8 next-tile loads issue at p0 (target buffer's last read was prev-iter
// p23, behind two barriers). vmcnt ledger (per wave, 2 loads/unit):
//   enter iter: 4 outstanding [B1,A1] -> p0 issues 8 -> 12
//   p0-end  VM_FENCE(10): cur B1 landed   (lead ~4 phases)
//   p1-end  VM_FENCE(8):  cur A1 landed   (lead ~5 phases)
//   p23-end VM_FENCE(4):  next A0,B0 landed -> back to 4. Never <4 in loop.
// Phase->unit map: p0 reads A rows 0..127 (unit A0) + B0; p1 reads B1;
// p23 reads A rows 128..255 (unit A1), reuses b0f/b1f from regs.
__global__ __launch_bounds__(512, 2) void gemm12_kernel(
    const unsigned short* __restrict__ A, const unsigned short* __restrict__ W0t,
    const unsigned short* __restrict__ W1t, const int* __restrict__ offsets,
    const int* __restrict__ tstart, unsigned short* __restrict__ inter) {
  extern __shared__ unsigned char smem[];
  int bx = blockIdx.x;
  if (bx >= tstart[NE]) return;
  int e = 0;
#pragma unroll
  for (int k = 1; k < NE; k++) if (tstart[k] <= bx) e = k;
  int row0 = offsets[e], row_end = offsets[e + 1];
  int tile_r0 = row0 + (bx - tstart[e]) * 256;
  if (tile_r0 >= row_end) return;
  int colb = blockIdx.y * 128;

  int tid = threadIdx.x;
  int wave = tid >> 6, lane = tid & 63;
  int wm = wave >> 2, wn = wave & 3;   // wm: 64-row slice within 128-half; wn: 32-col slice
  int l31 = lane & 31;
  int khalf = (lane >> 5) * 16;        // byte offset: which 8-elem half of a 16-K step

  const unsigned short* Ab = A + (size_t)tile_r0 * DIM;
  const unsigned short* B0b = W0t + ((size_t)e * MDIM + colb) * DIM;
  const unsigned short* B1b = W1t + ((size_t)e * MDIM + colb) * DIM;

  f32x16 acc0[2][2], acc1[2][2];   // [half][rb(32-row block)]
#pragma unroll
  for (int i = 0; i < 2; i++)
#pragma unroll
    for (int j = 0; j < 2; j++) {
      acc0[i][j] = (f32x16)(0.f);
      acc1[i][j] = (f32x16)(0.f);
    }
  bf16x8 af[2][4], b0f[4], b1f[4];   // [rb][kk] / [kk]; kk = 16-wide K step

  // prologue: tile 0 -> buf0, issue order A0,B0,B1,A1
  stage_unit(Ab, DIM, smem + 0, tid);
  stage_unit(B0b, DIM, smem + 32768, tid);
  stage_unit(B1b, DIM, smem + 49152, tid);
  stage_unit(Ab + (size_t)128 * DIM, DIM, smem + 16384, tid);
  VM_FENCE(4);   // A0,B0 landed; B1,A1 in flight
  BARRIER();

  for (int t = 0; t < 32; t++) {
    unsigned char* S = smem + (t & 1) * 65536;
    unsigned char* P = smem + ((t & 1) ^ 1) * 65536;
    int kn = (t < 31 ? t + 1 : t) * 64;   // clamp keeps vmcnt counts uniform
    // ---- p0: issue ALL next-tile stages; read A-half0 + B0; MFMA W0 x half0
    stage_unit(Ab + kn, DIM, P, tid);
    stage_unit(B0b + kn, DIM, P + 32768, tid);
    stage_unit(B1b + kn, DIM, P + 49152, tid);
    stage_unit(Ab + (size_t)128 * DIM + kn, DIM, P + 16384, tid);
#pragma unroll
    for (int rb = 0; rb < 2; rb++)
#pragma unroll
      for (int kk = 0; kk < 4; kk++)
        af[rb][kk] = ldsfrag(S, wm * 64 + rb * 32 + l31, kk * 32 + khalf);
#pragma unroll
    for (int kk = 0; kk < 4; kk++)
      b0f[kk] = ldsfrag(S + 32768, wn * 32 + l31, kk * 32 + khalf);
    BARRIER();
    __builtin_amdgcn_s_setprio(1);
#pragma unroll
    for (int kk = 0; kk < 4; kk++)
#pragma unroll
      for (int rb = 0; rb < 2; rb++)
        acc0[0][rb] = __builtin_amdgcn_mfma_f32_32x32x16_bf16(af[rb][kk], b0f[kk], acc0[0][rb], 0, 0, 0);
    __builtin_amdgcn_s_setprio(0);
    VM_FENCE(10);  // cur B1 landed
    BARRIER();
    // ---- p1: read B1; MFMA W1 x half0
#pragma unroll
    for (int kk = 0; kk < 4; kk++)
      b1f[kk] = ldsfrag(S + 49152, wn * 32 + l31, kk * 32 + khalf);
    BARRIER();
    __builtin_amdgcn_s_setprio(1);
#pragma unroll
    for (int kk = 0; kk < 4; kk++)
#pragma unroll
      for (int rb = 0; rb < 2; rb++)
        acc1[0][rb] = __builtin_amdgcn_mfma_f32_32x32x16_bf16(af[rb][kk], b1f[kk], acc1[0][rb], 0, 0, 0);
    __builtin_amdgcn_s_setprio(0);
    VM_FENCE(8);   // cur A1 landed
    BARRIER();
    // ---- p23: read A-half1; MFMA W0 x half1 then W1 x half1 (b0f/b1f reused)
#pragma unroll
    for (int rb = 0; rb < 2; rb++)
#pragma unroll
      for (int kk = 0; kk < 4; kk++)
        af[rb][kk] = ldsfrag(S, 128 + wm * 64 + rb * 32 + l31, kk * 32 + khalf);
    BARRIER();
    __builtin_amdgcn_s_setprio(1);
#pragma unroll
    for (int kk = 0; kk < 4; kk++)
#pragma unroll
      for (int rb = 0; rb < 2; rb++)
        acc0[1][rb] = __builtin_amdgcn_mfma_f32_32x32x16_bf16(af[rb][kk], b0f[kk], acc0[1][rb], 0, 0, 0);
#pragma unroll
    for (int kk = 0; kk < 4; kk++)
#pragma unroll
      for (int rb = 0; rb < 2; rb++)
        acc1[1][rb] = __builtin_amdgcn_mfma_f32_32x32x16_bf16(af[rb][kk], b1f[kk], acc1[1][rb], 0, 0, 0);
    __builtin_amdgcn_s_setprio(0);
    VM_FENCE(4);   // next A0,B0 landed; next B1,A1 stay in flight
    BARRIER();
  }
  VM_FENCE(0);  // drain clamped last-iter stages before LDS dealloc

  // epilogue: silu(h0)*h1 -> inter (bf16).
  // 32x32 C/D: col = lane&31, row = (reg&3) + 8*(reg>>2) + 4*(lane>>5)
  int rbase = 4 * (lane >> 5);
#pragma unroll
  for (int half = 0; half < 2; half++)
#pragma unroll
    for (int rb = 0; rb < 2; rb++)
#pragma unroll
      for (int reg = 0; reg < 16; reg++) {
        int grow = tile_r0 + half * 128 + wm * 64 + rb * 32 + (reg & 3) + 8 * (reg >> 2) + rbase;
        if (grow < row_end) {
          float h0 = acc0[half][rb][reg];
          float h1 = acc1[half][rb][reg];
          float g = h0 / (1.0f + __expf(-h0));
          inter[(size_t)grow * MDIM + colb + wn * 32 + l31] = f2bf(g * h1);
        }
      }
}

// ---------------- GEMM3: out_sorted = inter @ wo ---------------------------
// Same 3-phase deep-prefetch schedule, 32x32x16 MFMA: BM=256, BN=256, BK=64.
// Units A0,B0,B1,A1. p0 = q00 (A-h0, B-n0); p1 = q01 (B-n1); p23 = q10+q11
// (A-h1; B frags reused). Same vmcnt ledger 10/8/4.
__global__ __launch_bounds__(512, 2) void gemm3_kernel(
    const unsigned short* __restrict__ A, const unsigned short* __restrict__ Wot,
    const int* __restrict__ offsets, const int* __restrict__ tstart,
    float* __restrict__ out_sorted) {
  extern __shared__ unsigned char smem[];
  int bx = blockIdx.x;
  if (bx >= tstart[NE]) return;
  int e = 0;
#pragma unroll
  for (int k = 1; k < NE; k++) if (tstart[k] <= bx) e = k;
  int row0 = offsets[e], row_end = offsets[e + 1];
  int tile_r0 = row0 + (bx - tstart[e]) * 256;
  if (tile_r0 >= row_end) return;
  int col0 = blockIdx.y * 256;

  int tid = threadIdx.x;
  int wave = tid >> 6, lane = tid & 63;
  int wm = wave >> 2, wn = wave & 3;
  int l31 = lane & 31;
  int khalf = (lane >> 5) * 16;

  const unsigned short* Ab = A + (size_t)tile_r0 * MDIM;
  const unsigned short* Bb = Wot + ((size_t)e * DIM + col0) * MDIM;

  f32x16 acc[2][2][2];   // [mh][nh][rb]
#pragma unroll
  for (int i = 0; i < 2; i++)
#pragma unroll
    for (int j = 0; j < 2; j++)
#pragma unroll
      for (int r = 0; r < 2; r++) acc[i][j][r] = (f32x16)(0.f);
  bf16x8 af[2][4], bf0[4], bf1[4];

  stage_unit(Ab, MDIM, smem + 0, tid);
  stage_unit(Bb, MDIM, smem + 32768, tid);
  stage_unit(Bb + (size_t)128 * MDIM, MDIM, smem + 49152, tid);
  stage_unit(Ab + (size_t)128 * MDIM, MDIM, smem + 16384, tid);
  VM_FENCE(4);
  BARRIER();

  for (int t = 0; t < 16; t++) {
    unsigned char* S = smem + (t & 1) * 65536;
    unsigned char* P = smem + ((t & 1) ^ 1) * 65536;
    int kn = (t < 15 ? t + 1 : t) * 64;
    // ---- p0: issue ALL next-tile stages; read A-h0 + B-n0; MFMA q00
    stage_unit(Ab + kn, MDIM, P, tid);
    stage_unit(Bb + kn, MDIM, P + 32768, tid);
    stage_unit(Bb + (size_t)128 * MDIM + kn, MDIM, P + 49152, tid);
    stage_unit(Ab + (size_t)128 * MDIM + kn, MDIM, P + 16384, tid);
#pragma unroll
    for (int rb = 0; rb < 2; rb++)
#pragma unroll
      for (int kk = 0; kk < 4; kk++)
        af[rb][kk] = ldsfrag(S, wm * 64 + rb * 32 + l31, kk * 32 + khalf);
#pragma unroll
    for (int kk = 0; kk < 4; kk++)
      bf0[kk] = ldsfrag(S + 32768, wn * 32 + l31, kk * 32 + khalf);
    BARRIER();
    __builtin_amdgcn_s_setprio(1);
#pragma unroll
    for (int kk = 0; kk < 4; kk++)
#pragma unroll
      for (int rb = 0; rb < 2; rb++)
        acc[0][0][rb] = __builtin_amdgcn_mfma_f32_32x32x16_bf16(af[rb][kk], bf0[kk], acc[0][0][rb], 0, 0, 0);
    __builtin_amdgcn_s_setprio(0);
    VM_FENCE(10);  // cur B1 landed
    BARRIER();
    // ---- p1: read B-n1; MFMA q01
#pragma unroll
    for (int kk = 0; kk < 4; kk++)
      bf1[kk] = ldsfrag(S + 32768, 128 + wn * 32 + l31, kk * 32 + khalf);
    BARRIER();
    __builtin_amdgcn_s_setprio(1);
#pragma unroll
    for (int kk = 0; kk < 4; kk++)
#pragma unroll
      for (int rb = 0; rb < 2; rb++)
        acc[0][1][rb] = __builtin_amdgcn_mfma_f32_32x32x16_bf16(af[rb][kk], bf1[kk], acc[0][1][rb], 0, 0, 0);
    __builtin_amdgcn_s_setprio(0);
    VM_FENCE(8);   // cur A1 landed
    BARRIER();
    // ---- p23: read A-h1; MFMA q10 then q11 (bf0/bf1 reused)
#pragma unroll
    for (int rb = 0; rb < 2; rb++)
#pragma unroll
      for (int kk = 0; kk < 4; kk++)
        af[rb][kk] = ldsfrag(S, 128 + wm * 64 + rb * 32 + l31, kk * 32 + khalf);
    BARRIER();
    __builtin_amdgcn_s_setprio(1);
#pragma unroll
    for (int kk = 0; kk < 4; kk++)
#pragma unroll
      for (int rb = 0; rb < 2; rb++)
        acc[1][0][rb] = __builtin_amdgcn_mfma_f32_32x32x16_bf16(af[rb][kk], bf0[kk], acc[1][0][rb], 0, 0, 0);
#pragma unroll
    for (int kk = 0; kk < 4; kk++)
#pragma unroll
      for (int rb = 0; rb < 2; rb++)
        acc[1][1][rb] = __builtin_amdgcn_mfma_f32_32x32x16_bf16(af[rb][kk], bf1[kk], acc[1][1][rb], 0, 0, 0);
    __builtin_amdgcn_s_setprio(0);
    VM_FENCE(4);   // next A0,B0 landed
    BARRIER();
  }
  VM_FENCE(0);

  // epilogue: plain f32 stores.
  // 32x32 C/D: col = lane&31, row = (reg&3) + 8*(reg>>2) + 4*(lane>>5)
  int rbase = 4 * (lane >> 5);
#pragma unroll
  for (int mh = 0; mh < 2; mh++)
#pragma unroll
    for (int rb = 0; rb < 2; rb++)
#pragma unroll
      for (int reg = 0; reg < 16; reg++) {
        int grow = tile_r0 + mh * 128 + wm * 64 + rb * 32 + (reg & 3) + 8 * (reg >> 2) + rbase;
        if (grow < row_end) {
          float* orow = out_sorted + (size_t)grow * DIM + col0 + wn * 32 + l31;
#pragma unroll
          for (int nh = 0; nh < 2; nh++)
            orow[nh * 128] = acc[mh][nh][rb][reg];
        }
      }
}

// ---------------- combine: out[t] = w0*os[slot0] + w1*os[slot1] -------------
__global__ __launch_bounds__(256) void combine_kernel(
    const float* __restrict__ os, const int* __restrict__ tok_slot,
    const float* __restrict__ tok_w, float* __restrict__ out) {
  int t = blockIdx.x * 4 + (threadIdx.x >> 6);
  int lane = threadIdx.x & 63;
  int s0 = tok_slot[2 * t], s1 = tok_slot[2 * t + 1];
  float w0 = tok_w[2 * t], w1 = tok_w[2 * t + 1];
  const float4* a = (const float4*)(os + (size_t)s0 * DIM);
  const float4* b = (const float4*)(os + (size_t)s1 * DIM);
  float4* o = (float4*)(out + (size_t)t * DIM);
#pragma unroll
  for (int i = lane; i < DIM / 4; i += 64) {
    float4 va = a[i], vb = b[i];
    float4 r;
    r.x = w0 * va.x + w1 * vb.x;
    r.y = w0 * va.y + w1 * vb.y;
    r.z = w0 * va.z + w1 * vb.z;
    r.w = w0 * va.w + w1 * vb.w;
    o[i] = r;
  }
}

// ---------------------------------------------------------------------------
extern "C" void kernel_launch(void* const* d_in, const int* in_sizes, int n_in,
                              void* d_out, int out_size, void* d_ws, size_t ws_size,
                              hipStream_t stream) {
  const float* x   = (const float*)d_in[0];
  const float* wg  = (const float*)d_in[1];
  const float* wi0 = (const float*)d_in[2];
  const float* wi1 = (const float*)d_in[3];
  const float* wo  = (const float*)d_in[4];
  float* out = (float*)d_out;

  // opt-in to 128 KiB dynamic LDS (call unconditionally; cheap host-side op)
  (void)hipFuncSetAttribute(reinterpret_cast<const void*>(gemm12_kernel),
                            hipFuncAttributeMaxDynamicSharedMemorySize, 131072);
  (void)hipFuncSetAttribute(reinterpret_cast<const void*>(gemm3_kernel),
                            hipFuncAttributeMaxDynamicSharedMemorySize, 131072);

  char* ws = (char*)d_ws;
  size_t off = 0;
  auto alloc = [&](size_t bytes) -> void* {
    void* p = ws + off;
    off = (off + bytes + 255) & ~(size_t)255;
    return p;
  };
  int*   offsets  = (int*)alloc((NE + 1) * 4);
  int*   tstart   = (int*)alloc((NE + 1) * 4);
  int*   tok_eid  = (int*)alloc((size_t)2 * T_TOK * 4);
  float* tok_w    = (float*)alloc((size_t)2 * T_TOK * 4);
  int*   tok_slot = (int*)alloc((size_t)2 * T_TOK * 4);
  unsigned short* inter    = (unsigned short*)alloc((size_t)CAP * MDIM * 2);
  // sorted_x + W0t + W1t form one contiguous 135.3 MB window; after gemm12
  // they are dead and out_sorted (16384*DIM*4 = 134.22 MB) aliases the window.
  unsigned short* sorted_x = (unsigned short*)alloc((size_t)CAP * DIM * 2);
  unsigned short* W0t      = (unsigned short*)alloc((size_t)NE * MDIM * DIM * 2);
  unsigned short* W1t      = (unsigned short*)alloc((size_t)NE * MDIM * DIM * 2);
  unsigned short* Wot      = (unsigned short*)alloc((size_t)NE * DIM * MDIM * 2);
  float* out_sorted = (float*)sorted_x;  // alias (see above)

  router_kernel<<<T_TOK / 16, 256, 0, stream>>>(x, wg, tok_eid, tok_w);
  plan_kernel<<<1, 256, 0, stream>>>(tok_eid, offsets, tstart, tok_slot);
  dispatch_kernel<<<T_TOK, 256, 0, stream>>>(x, tok_slot, sorted_x);
  // wi_0 [E][D][M] -> W0t [E][M][D]; wi_1 likewise; wo [E][M][D] -> Wot [E][D][M]
  transpose_cast_kernel<<<dim3(MDIM / 32, DIM / 32, NE), 256, 0, stream>>>(wi0, W0t, DIM, MDIM);
  transpose_cast_kernel<<<dim3(MDIM / 32, DIM / 32, NE), 256, 0, stream>>>(wi1, W1t, DIM, MDIM);
  transpose_cast_kernel<<<dim3(DIM / 32, MDIM / 32, NE), 256, 0, stream>>>(wo, Wot, MDIM, DIM);

  gemm12_kernel<<<dim3(MAXT, MDIM / 128, 1), 512, 131072, stream>>>(
      sorted_x, W0t, W1t, offsets, tstart, inter);
  gemm3_kernel<<<dim3(MAXT, DIM / 256, 1), 512, 131072, stream>>>(
      inter, Wot, offsets, tstart, out_sorted);
  combine_kernel<<<T_TOK / 4, 256, 0, stream>>>(out_sorted, tok_slot, tok_w, out);
}

// Round 4
// 652.135 us; speedup vs baseline: 1.0323x; 1.0323x over previous
//
#include <hip/hip_runtime.h>
#include <hip/hip_bf16.h>
#include <math.h>

// Problem dims (fixed by reference)
#define T_TOK 8192          // B*S tokens
#define DIM   2048          // D
#define NE    8             // experts
#define MDIM  1024          // intermediate
#define TK    16384         // T*K token copies
#define CAP   (TK + 256)    // slack rows so 256-row edge tiles can over-read safely
#define MAXT  72            // sum_e ceil(cnt_e/256) <= 64 + 8

typedef __attribute__((ext_vector_type(8))) short bf16x8;
typedef __attribute__((ext_vector_type(4))) float f32x4;

typedef __attribute__((address_space(3))) unsigned char* lds_ptr_t;
typedef const __attribute__((address_space(1))) unsigned char* glb_ptr_t;

__device__ __forceinline__ unsigned short f2bf(float f) {
  union { float f; unsigned u; } v; v.f = f;
  unsigned r = v.u + 0x7fffu + ((v.u >> 16) & 1u);  // round-to-nearest-even
  return (unsigned short)(r >> 16);
}

__device__ __forceinline__ void gload_lds16(const void* g, void* l) {
  // each lane loads 16B from its own global addr; lands at lds_base + lane*16
  __builtin_amdgcn_global_load_lds((glb_ptr_t)g, (lds_ptr_t)l, 16, 0, 0);
}

#define VM_FENCE(n) asm volatile("s_waitcnt vmcnt(" #n ")" ::: "memory")
#define BARRIER() __builtin_amdgcn_s_barrier()

// Stage one 128x64 bf16 unit (16 KB) into LDS, linear dest, INVERSE-swizzled
// global source so that a swizzled ds_read (byte ^= (row&7)<<4) sees the right
// data (rule #21: both-sides-or-neither). 512 threads x 2 insts x 16B = 16 KB.
// Per wave this is exactly 2 vmcnt increments.
__device__ __forceinline__ void stage_unit(const unsigned short* __restrict__ src,
                                           int ld, unsigned char* lds, int tid) {
#pragma unroll
  for (int j = 0; j < 2; j++) {
    int idx = j * 512 + tid;
    int row = idx >> 3;                       // 0..127
    int gslot = (idx & 7) ^ (row & 7);        // inverse swizzle on source
    gload_lds16(src + (size_t)row * ld + gslot * 8, lds + ((idx & ~63) << 4));
  }
}

// Swizzled LDS fragment read: row stride 128B, XOR bits 4-6 with row&7.
// 16x16x32 frag pattern: 16-lane group spans 16 rows x 4 col-slots ->
// worst 2-way bank aliasing (free, m136). (32x32 frag reads are a structural
// 4-way conflict in this geometry -- measured R3, do not use.)
__device__ __forceinline__ bf16x8 ldsfrag(const unsigned char* base, int row, int kb) {
  return *(const bf16x8*)(base + row * 128 + (kb ^ ((row & 7) << 4)));
}

// ---------------- router: fp64 logits, top-2, softmax weights ----------------
__global__ __launch_bounds__(256) void router_kernel(
    const float* __restrict__ x, const float* __restrict__ wg,
    int* __restrict__ tok_eid, float* __restrict__ tok_w) {
  __shared__ float wgT[NE][1024];  // 32 KB, one D-half at a time
  int tid = threadIdx.x;
  int wave = tid >> 6, lane = tid & 63;
  int t0 = blockIdx.x * 16 + wave * 4;  // 512 blocks x 4 waves x 4 tokens = 8192

  double acc[4][NE];
#pragma unroll
  for (int tt = 0; tt < 4; tt++)
#pragma unroll
    for (int e = 0; e < NE; e++) acc[tt][e] = 0.0;

  for (int p = 0; p < 2; p++) {
    __syncthreads();
#pragma unroll
    for (int j = tid; j < 2048; j += 256) {
      float4 v = ((const float4*)wg)[p * 2048 + j];
      int d = j >> 1, h = (j & 1) * 4;
      wgT[h + 0][d] = v.x;
      wgT[h + 1][d] = v.y;
      wgT[h + 2][d] = v.z;
      wgT[h + 3][d] = v.w;
    }
    __syncthreads();
#pragma unroll
    for (int it = 0; it < 4; it++) {
      int dd = it * 256 + lane * 4;
      int gd = p * 1024 + dd;
      float4 wf[NE];
#pragma unroll
      for (int e = 0; e < NE; e++) wf[e] = *(const float4*)&wgT[e][dd];
#pragma unroll
      for (int tt = 0; tt < 4; tt++) {
        float4 xv = *(const float4*)(x + (size_t)(t0 + tt) * DIM + gd);
#pragma unroll
        for (int e = 0; e < NE; e++) {
          acc[tt][e] += (double)xv.x * (double)wf[e].x;
          acc[tt][e] += (double)xv.y * (double)wf[e].y;
          acc[tt][e] += (double)xv.z * (double)wf[e].z;
          acc[tt][e] += (double)xv.w * (double)wf[e].w;
        }
      }
    }
  }
#pragma unroll
  for (int tt = 0; tt < 4; tt++)
#pragma unroll
    for (int e = 0; e < NE; e++) {
      double v = acc[tt][e];
#pragma unroll
      for (int off = 32; off > 0; off >>= 1) v += __shfl_down(v, off, 64);
      acc[tt][e] = v;
    }
  if (lane == 0) {
#pragma unroll
    for (int tt = 0; tt < 4; tt++) {
      int t = t0 + tt;
      int b0 = 0; double l0 = acc[tt][0];
#pragma unroll
      for (int e = 1; e < NE; e++) { if (acc[tt][e] > l0) { l0 = acc[tt][e]; b0 = e; } }
      int b1 = -1; double l1 = -1.0e300;
#pragma unroll
      for (int e = 0; e < NE; e++) { if (e != b0 && acc[tt][e] > l1) { l1 = acc[tt][e]; b1 = e; } }
      double w0 = 1.0 / (1.0 + exp(l1 - l0));
      tok_eid[2 * t]     = b0;
      tok_eid[2 * t + 1] = b1;
      tok_w[2 * t]     = (float)w0;
      tok_w[2 * t + 1] = (float)(1.0 - w0);
    }
  }
}

// ---------------- plan: counting sort of tok_eid -> offsets/tstart/tok_slot --
__global__ __launch_bounds__(256) void plan_kernel(
    const int* __restrict__ tok_eid, int* __restrict__ offsets,
    int* __restrict__ tstart, int* __restrict__ tok_slot) {
  __shared__ int cnt[256][NE];
  __shared__ int pre[256][NE];
  __shared__ int tot[NE];
  __shared__ int off_sh[NE + 1];
  int th = threadIdx.x;
  int c[NE];
#pragma unroll
  for (int k = 0; k < NE; k++) c[k] = 0;
  for (int i = 0; i < TK / 256; i++) {
    int e = tok_eid[i * 256 + th];
#pragma unroll
    for (int k = 0; k < NE; k++) c[k] += (e == k) ? 1 : 0;
  }
#pragma unroll
  for (int k = 0; k < NE; k++) cnt[th][k] = c[k];
  __syncthreads();
  if (th < NE) {
    int run = 0;
#pragma unroll 4
    for (int i = 0; i < 256; i++) { pre[i][th] = run; run += cnt[i][th]; }
    tot[th] = run;
  }
  __syncthreads();
  if (th == 0) {
    int s = 0, ts = 0;
    for (int e = 0; e < NE; e++) {
      off_sh[e] = s; offsets[e] = s; s += tot[e];
      tstart[e] = ts; ts += (tot[e] + 255) / 256;   // 256-row tiles
    }
    offsets[NE] = s; off_sh[NE] = s; tstart[NE] = ts;
  }
  __syncthreads();
  int b[NE];
#pragma unroll
  for (int k = 0; k < NE; k++) b[k] = off_sh[k] + pre[th][k];
  for (int i = 0; i < TK / 256; i++) {
    int idx = i * 256 + th;
    int e = tok_eid[idx];
    int slot = 0;
#pragma unroll
    for (int k = 0; k < NE; k++) {
      slot = (e == k) ? b[k] : slot;
      b[k] += (e == k) ? 1 : 0;
    }
    tok_slot[idx] = slot;
  }
}

// ---------------- dispatch: gather x -> sorted_x (bf16), atomic-free --------
__global__ __launch_bounds__(256) void dispatch_kernel(
    const float* __restrict__ x, const int* __restrict__ tok_slot,
    unsigned short* __restrict__ sorted_x) {
  int t = blockIdx.x;
  size_t s0 = (size_t)tok_slot[2 * t] * DIM;
  size_t s1 = (size_t)tok_slot[2 * t + 1] * DIM;
  const float4* xr = (const float4*)(x + (size_t)t * DIM);
#pragma unroll
  for (int i = threadIdx.x; i < DIM / 4; i += 256) {
    float4 v = xr[i];
    ushort4 b;
    b.x = f2bf(v.x); b.y = f2bf(v.y); b.z = f2bf(v.z); b.w = f2bf(v.w);
    *(ushort4*)(sorted_x + s0 + (size_t)i * 4) = b;
    *(ushort4*)(sorted_x + s1 + (size_t)i * 4) = b;
  }
}

// ---------------- weight cast + transpose: f32 [R][C] -> bf16 [C][R] --------
__global__ __launch_bounds__(256) void transpose_cast_kernel(
    const float* __restrict__ in, unsigned short* __restrict__ out, int R, int C) {
  __shared__ unsigned short tile[32][33];
  int e = blockIdx.z;
  const float* inp = in + (size_t)e * R * C;
  unsigned short* outp = out + (size_t)e * R * C;
  int c0 = blockIdx.x * 32, r0 = blockIdx.y * 32;
  int tx = threadIdx.x & 31, ty = threadIdx.x >> 5;
#pragma unroll
  for (int i = 0; i < 32; i += 8)
    tile[ty + i][tx] = f2bf(inp[(size_t)(r0 + ty + i) * C + (c0 + tx)]);
  __syncthreads();
#pragma unroll
  for (int i = 0; i < 32; i += 8)
    outp[(size_t)(c0 + ty + i) * R + (r0 + tx)] = tile[tx][ty + i];
}

// ---------------- GEMM12: inter = silu(A@wi0) * (A@wi1) --------------------
// 4-phase schedule, 16x16x32 MFMA (conflict-free frag reads), DEEP PREFETCH:
// BM=256, BK=64, 512 thr / 8 waves, 128 KiB dbuf LDS {A0|A1|B0|B1} x2.
// Phase->unit map: p0 reads A rows 0..127 (unit A0) + B0; p1 reads B1;
// p2 reads A rows 128..255 (unit A1); p3 reads nothing (reuses regs).
// ALL 4 next-tile units issue at p0 (target buffer last read prev-iter p2,
// two barriers back). vmcnt ledger (2 loads/unit/wave):
//   enter iter: 4 outstanding [B1,A1] -> p0 issues 8 -> 12
//   p0-end VM_FENCE(10): cur B1 landed  (~4-phase lead)
//   p1-end VM_FENCE(8):  cur A1 landed  (~5-phase lead)
//   p3-end VM_FENCE(4):  next A0,B0 landed -> back to 4. Never <4 in loop.
__global__ __launch_bounds__(512, 2) void gemm12_kernel(
    const unsigned short* __restrict__ A, const unsigned short* __restrict__ W0t,
    const unsigned short* __restrict__ W1t, const int* __restrict__ offsets,
    const int* __restrict__ tstart, unsigned short* __restrict__ inter) {
  extern __shared__ unsigned char smem[];
  int bx = blockIdx.x;
  if (bx >= tstart[NE]) return;
  int e = 0;
#pragma unroll
  for (int k = 1; k < NE; k++) if (tstart[k] <= bx) e = k;
  int row0 = offsets[e], row_end = offsets[e + 1];
  int tile_r0 = row0 + (bx - tstart[e]) * 256;
  if (tile_r0 >= row_end) return;
  int colb = blockIdx.y * 128;

  int tid = threadIdx.x;
  int wave = tid >> 6, lane = tid & 63;
  int wm = wave >> 2, wn = wave & 3;   // wm: 64-row slice within 128-half; wn: 32-col slice
  int l15 = lane & 15, grp16 = (lane >> 4) * 16;

  const unsigned short* Ab = A + (size_t)tile_r0 * DIM;
  const unsigned short* B0b = W0t + ((size_t)e * MDIM + colb) * DIM;
  const unsigned short* B1b = W1t + ((size_t)e * MDIM + colb) * DIM;

  f32x4 acc0[8][2], acc1[8][2];   // [half*4+mi][ni]
#pragma unroll
  for (int i = 0; i < 8; i++)
#pragma unroll
    for (int j = 0; j < 2; j++) {
      acc0[i][j] = (f32x4){0.f, 0.f, 0.f, 0.f};
      acc1[i][j] = (f32x4){0.f, 0.f, 0.f, 0.f};
    }
  bf16x8 af[4][2], b0f[2][2], b1f[2][2];

  // prologue: tile 0 -> buf0, issue order A0,B0,B1,A1
  stage_unit(Ab, DIM, smem + 0, tid);
  stage_unit(B0b, DIM, smem + 32768, tid);
  stage_unit(B1b, DIM, smem + 49152, tid);
  stage_unit(Ab + (size_t)128 * DIM, DIM, smem + 16384, tid);
  VM_FENCE(4);   // A0,B0 landed; B1,A1 in flight
  BARRIER();

  for (int t = 0; t < 32; t++) {
    unsigned char* S = smem + (t & 1) * 65536;
    unsigned char* P = smem + ((t & 1) ^ 1) * 65536;
    int kn = (t < 31 ? t + 1 : t) * 64;   // clamp keeps vmcnt counts uniform
    // ---- p0: issue ALL next-tile stages; read A half0 + B0; MFMA W0 x half0
    stage_unit(Ab + kn, DIM, P, tid);
    stage_unit(B0b + kn, DIM, P + 32768, tid);
    stage_unit(B1b + kn, DIM, P + 49152, tid);
    stage_unit(Ab + (size_t)128 * DIM + kn, DIM, P + 16384, tid);
#pragma unroll
    for (int mi = 0; mi < 4; mi++) {
      int r = wm * 64 + mi * 16 + l15;              // rows 0..127 = unit A0
#pragma unroll
      for (int ks = 0; ks < 2; ks++) af[mi][ks] = ldsfrag(S, r, ks * 64 + grp16);
    }
#pragma unroll
    for (int ni = 0; ni < 2; ni++) {
      int r = wn * 32 + ni * 16 + l15;              // rows 0..127 = unit B0
#pragma unroll
      for (int ks = 0; ks < 2; ks++) b0f[ni][ks] = ldsfrag(S + 32768, r, ks * 64 + grp16);
    }
    BARRIER();
    __builtin_amdgcn_s_setprio(1);
#pragma unroll
    for (int ks = 0; ks < 2; ks++)
#pragma unroll
      for (int mi = 0; mi < 4; mi++)
#pragma unroll
        for (int ni = 0; ni < 2; ni++)
          acc0[mi][ni] = __builtin_amdgcn_mfma_f32_16x16x32_bf16(af[mi][ks], b0f[ni][ks], acc0[mi][ni], 0, 0, 0);
    __builtin_amdgcn_s_setprio(0);
    VM_FENCE(10);  // cur B1 landed (read at p1 start)
    BARRIER();
    // ---- p1: read B1 frags; MFMA W1 x half0
#pragma unroll
    for (int ni = 0; ni < 2; ni++) {
      int r = wn * 32 + ni * 16 + l15;              // rows 0..127 = unit B1
#pragma unroll
      for (int ks = 0; ks < 2; ks++) b1f[ni][ks] = ldsfrag(S + 49152, r, ks * 64 + grp16);
    }
    BARRIER();
    __builtin_amdgcn_s_setprio(1);
#pragma unroll
    for (int ks = 0; ks < 2; ks++)
#pragma unroll
      for (int mi = 0; mi < 4; mi++)
#pragma unroll
        for (int ni = 0; ni < 2; ni++)
          acc1[mi][ni] = __builtin_amdgcn_mfma_f32_16x16x32_bf16(af[mi][ks], b1f[ni][ks], acc1[mi][ni], 0, 0, 0);
    __builtin_amdgcn_s_setprio(0);
    VM_FENCE(8);   // cur A1 landed (read at p2 start)
    BARRIER();
    // ---- p2: read A half1 frags; MFMA W0 x half1 (b0f reused)
#pragma unroll
    for (int mi = 0; mi < 4; mi++) {
      int r = 128 + wm * 64 + mi * 16 + l15;        // rows 128..255 = unit A1
#pragma unroll
      for (int ks = 0; ks < 2; ks++) af[mi][ks] = ldsfrag(S, r, ks * 64 + grp16);
    }
    BARRIER();
    __builtin_amdgcn_s_setprio(1);
#pragma unroll
    for (int ks = 0; ks < 2; ks++)
#pragma unroll
      for (int mi = 0; mi < 4; mi++)
#pragma unroll
        for (int ni = 0; ni < 2; ni++)
          acc0[4 + mi][ni] = __builtin_amdgcn_mfma_f32_16x16x32_bf16(af[mi][ks], b0f[ni][ks], acc0[4 + mi][ni], 0, 0, 0);
    __builtin_amdgcn_s_setprio(0);
    BARRIER();
    // ---- p3: MFMA W1 x half1 (af, b1f reused)
    __builtin_amdgcn_s_setprio(1);
#pragma unroll
    for (int ks = 0; ks < 2; ks++)
#pragma unroll
      for (int mi = 0; mi < 4; mi++)
#pragma unroll
        for (int ni = 0; ni < 2; ni++)
          acc1[4 + mi][ni] = __builtin_amdgcn_mfma_f32_16x16x32_bf16(af[mi][ks], b1f[ni][ks], acc1[4 + mi][ni], 0, 0, 0);
    __builtin_amdgcn_s_setprio(0);
    VM_FENCE(4);   // next A0,B0 landed; next B1,A1 stay in flight
    BARRIER();
  }
  VM_FENCE(0);  // drain clamped last-iter stages

  // epilogue: silu(h0)*h1 -> inter (bf16). C/D: col=lane&15, row=(lane>>4)*4+reg
#pragma unroll
  for (int half = 0; half < 2; half++)
#pragma unroll
    for (int mi = 0; mi < 4; mi++)
#pragma unroll
      for (int reg = 0; reg < 4; reg++) {
        int grow = tile_r0 + half * 128 + wm * 64 + mi * 16 + (lane >> 4) * 4 + reg;
        if (grow < row_end) {
#pragma unroll
          for (int ni = 0; ni < 2; ni++) {
            float h0 = acc0[half * 4 + mi][ni][reg];
            float h1 = acc1[half * 4 + mi][ni][reg];
            float g = h0 / (1.0f + __expf(-h0));
            inter[(size_t)grow * MDIM + colb + wn * 32 + ni * 16 + l15] = f2bf(g * h1);
          }
        }
      }
}

// ---------------- GEMM3: out_sorted = inter @ wo ---------------------------
// Same 4-phase deep-prefetch schedule: BM=256, BN=256, BK=64.
// Quadrants == units: p0=q00 (A0,B0), p1=q01 (B1), p2=q10 (A1), p3=q11
// (reuse). Same vmcnt ledger 10/8/4.
__global__ __launch_bounds__(512, 2) void gemm3_kernel(
    const unsigned short* __restrict__ A, const unsigned short* __restrict__ Wot,
    const int* __restrict__ offsets, const int* __restrict__ tstart,
    float* __restrict__ out_sorted) {
  extern __shared__ unsigned char smem[];
  int bx = blockIdx.x;
  if (bx >= tstart[NE]) return;
  int e = 0;
#pragma unroll
  for (int k = 1; k < NE; k++) if (tstart[k] <= bx) e = k;
  int row0 = offsets[e], row_end = offsets[e + 1];
  int tile_r0 = row0 + (bx - tstart[e]) * 256;
  if (tile_r0 >= row_end) return;
  int col0 = blockIdx.y * 256;

  int tid = threadIdx.x;
  int wave = tid >> 6, lane = tid & 63;
  int wm = wave >> 2, wn = wave & 3;
  int l15 = lane & 15, grp16 = (lane >> 4) * 16;

  const unsigned short* Ab = A + (size_t)tile_r0 * MDIM;
  const unsigned short* Bb = Wot + ((size_t)e * DIM + col0) * MDIM;

  f32x4 acc[8][4];   // [mh*4+mi][nh*2+ni]
#pragma unroll
  for (int i = 0; i < 8; i++)
#pragma unroll
    for (int j = 0; j < 4; j++) acc[i][j] = (f32x4){0.f, 0.f, 0.f, 0.f};
  bf16x8 af[4][2], bfr[4][2];   // bfr[nh*2+ni]

  stage_unit(Ab, MDIM, smem + 0, tid);
  stage_unit(Bb, MDIM, smem + 32768, tid);
  stage_unit(Bb + (size_t)128 * MDIM, MDIM, smem + 49152, tid);
  stage_unit(Ab + (size_t)128 * MDIM, MDIM, smem + 16384, tid);
  VM_FENCE(4);
  BARRIER();

  for (int t = 0; t < 16; t++) {
    unsigned char* S = smem + (t & 1) * 65536;
    unsigned char* P = smem + ((t & 1) ^ 1) * 65536;
    int kn = (t < 15 ? t + 1 : t) * 64;
    // ---- p0: issue ALL next-tile stages; read A half0 + B nh0; MFMA q00
    stage_unit(Ab + kn, MDIM, P, tid);
    stage_unit(Bb + kn, MDIM, P + 32768, tid);
    stage_unit(Bb + (size_t)128 * MDIM + kn, MDIM, P + 49152, tid);
    stage_unit(Ab + (size_t)128 * MDIM + kn, MDIM, P + 16384, tid);
#pragma unroll
    for (int mi = 0; mi < 4; mi++) {
      int r = wm * 64 + mi * 16 + l15;              // unit A0
#pragma unroll
      for (int ks = 0; ks < 2; ks++) af[mi][ks] = ldsfrag(S, r, ks * 64 + grp16);
    }
#pragma unroll
    for (int ni = 0; ni < 2; ni++) {
      int r = wn * 32 + ni * 16 + l15;              // unit B0
#pragma unroll
      for (int ks = 0; ks < 2; ks++) bfr[ni][ks] = ldsfrag(S + 32768, r, ks * 64 + grp16);
    }
    BARRIER();
    __builtin_amdgcn_s_setprio(1);
#pragma unroll
    for (int ks = 0; ks < 2; ks++)
#pragma unroll
      for (int mi = 0; mi < 4; mi++)
#pragma unroll
        for (int ni = 0; ni < 2; ni++)
          acc[mi][ni] = __builtin_amdgcn_mfma_f32_16x16x32_bf16(af[mi][ks], bfr[ni][ks], acc[mi][ni], 0, 0, 0);
    __builtin_amdgcn_s_setprio(0);
    VM_FENCE(10);  // cur B1 landed
    BARRIER();
    // ---- p1: read B nh1; MFMA q01
#pragma unroll
    for (int ni = 0; ni < 2; ni++) {
      int r = 128 + wn * 32 + ni * 16 + l15;        // unit B1
#pragma unroll
      for (int ks = 0; ks < 2; ks++) bfr[2 + ni][ks] = ldsfrag(S + 32768, r, ks * 64 + grp16);
    }
    BARRIER();
    __builtin_amdgcn_s_setprio(1);
#pragma unroll
    for (int ks = 0; ks < 2; ks++)
#pragma unroll
      for (int mi = 0; mi < 4; mi++)
#pragma unroll
        for (int ni = 0; ni < 2; ni++)
          acc[mi][2 + ni] = __builtin_amdgcn_mfma_f32_16x16x32_bf16(af[mi][ks], bfr[2 + ni][ks], acc[mi][2 + ni], 0, 0, 0);
    __builtin_amdgcn_s_setprio(0);
    VM_FENCE(8);   // cur A1 landed
    BARRIER();
    // ---- p2: read A half1; MFMA q10 (bfr nh0 reused)
#pragma unroll
    for (int mi = 0; mi < 4; mi++) {
      int r = 128 + wm * 64 + mi * 16 + l15;        // unit A1
#pragma unroll
      for (int ks = 0; ks < 2; ks++) af[mi][ks] = ldsfrag(S, r, ks * 64 + grp16);
    }
    BARRIER();
    __builtin_amdgcn_s_setprio(1);
#pragma unroll
    for (int ks = 0; ks < 2; ks++)
#pragma unroll
      for (int mi = 0; mi < 4; mi++)
#pragma unroll
        for (int ni = 0; ni < 2; ni++)
          acc[4 + mi][ni] = __builtin_amdgcn_mfma_f32_16x16x32_bf16(af[mi][ks], bfr[ni][ks], acc[4 + mi][ni], 0, 0, 0);
    __builtin_amdgcn_s_setprio(0);
    BARRIER();
    // ---- p3: MFMA q11 (af, bfr nh1 reused)
    __builtin_amdgcn_s_setprio(1);
#pragma unroll
    for (int ks = 0; ks < 2; ks++)
#pragma unroll
      for (int mi = 0; mi < 4; mi++)
#pragma unroll
        for (int ni = 0; ni < 2; ni++)
          acc[4 + mi][2 + ni] = __builtin_amdgcn_mfma_f32_16x16x32_bf16(af[mi][ks], bfr[2 + ni][ks], acc[4 + mi][2 + ni], 0, 0, 0);
    __builtin_amdgcn_s_setprio(0);
    VM_FENCE(4);   // next A0,B0 landed
    BARRIER();
  }
  VM_FENCE(0);

  // epilogue: plain f32 stores
#pragma unroll
  for (int mh = 0; mh < 2; mh++)
#pragma unroll
    for (int mi = 0; mi < 4; mi++)
#pragma unroll
      for (int reg = 0; reg < 4; reg++) {
        int grow = tile_r0 + mh * 128 + wm * 64 + mi * 16 + (lane >> 4) * 4 + reg;
        if (grow < row_end) {
#pragma unroll
          for (int nh = 0; nh < 2; nh++) {
            float* orow = out_sorted + (size_t)grow * DIM + col0 + nh * 128 + wn * 32 + l15;
#pragma unroll
            for (int ni = 0; ni < 2; ni++)
              orow[ni * 16] = acc[mh * 4 + mi][nh * 2 + ni][reg];
          }
        }
      }
}

// ---------------- combine: out[t] = w0*os[slot0] + w1*os[slot1] -------------
__global__ __launch_bounds__(256) void combine_kernel(
    const float* __restrict__ os, const int* __restrict__ tok_slot,
    const float* __restrict__ tok_w, float* __restrict__ out) {
  int t = blockIdx.x * 4 + (threadIdx.x >> 6);
  int lane = threadIdx.x & 63;
  int s0 = tok_slot[2 * t], s1 = tok_slot[2 * t + 1];
  float w0 = tok_w[2 * t], w1 = tok_w[2 * t + 1];
  const float4* a = (const float4*)(os + (size_t)s0 * DIM);
  const float4* b = (const float4*)(os + (size_t)s1 * DIM);
  float4* o = (float4*)(out + (size_t)t * DIM);
#pragma unroll
  for (int i = lane; i < DIM / 4; i += 64) {
    float4 va = a[i], vb = b[i];
    float4 r;
    r.x = w0 * va.x + w1 * vb.x;
    r.y = w0 * va.y + w1 * vb.y;
    r.z = w0 * va.z + w1 * vb.z;
    r.w = w0 * va.w + w1 * vb.w;
    o[i] = r;
  }
}

// ---------------------------------------------------------------------------
extern "C" void kernel_launch(void* const* d_in, const int* in_sizes, int n_in,
                              void* d_out, int out_size, void* d_ws, size_t ws_size,
                              hipStream_t stream) {
  const float* x   = (const float*)d_in[0];
  const float* wg  = (const float*)d_in[1];
  const float* wi0 = (const float*)d_in[2];
  const float* wi1 = (const float*)d_in[3];
  const float* wo  = (const float*)d_in[4];
  float* out = (float*)d_out;

  // opt-in to 128 KiB dynamic LDS (call unconditionally; cheap host-side op)
  (void)hipFuncSetAttribute(reinterpret_cast<const void*>(gemm12_kernel),
                            hipFuncAttributeMaxDynamicSharedMemorySize, 131072);
  (void)hipFuncSetAttribute(reinterpret_cast<const void*>(gemm3_kernel),
                            hipFuncAttributeMaxDynamicSharedMemorySize, 131072);

  char* ws = (char*)d_ws;
  size_t off = 0;
  auto alloc = [&](size_t bytes) -> void* {
    void* p = ws + off;
    off = (off + bytes + 255) & ~(size_t)255;
    return p;
  };
  int*   offsets  = (int*)alloc((NE + 1) * 4);
  int*   tstart   = (int*)alloc((NE + 1) * 4);
  int*   tok_eid  = (int*)alloc((size_t)2 * T_TOK * 4);
  float* tok_w    = (float*)alloc((size_t)2 * T_TOK * 4);
  int*   tok_slot = (int*)alloc((size_t)2 * T_TOK * 4);
  unsigned short* inter    = (unsigned short*)alloc((size_t)CAP * MDIM * 2);
  // sorted_x + W0t + W1t form one contiguous 135.3 MB window; after gemm12
  // they are dead and out_sorted (16384*DIM*4 = 134.22 MB) aliases the window.
  unsigned short* sorted_x = (unsigned short*)alloc((size_t)CAP * DIM * 2);
  unsigned short* W0t      = (unsigned short*)alloc((size_t)NE * MDIM * DIM * 2);
  unsigned short* W1t      = (unsigned short*)alloc((size_t)NE * MDIM * DIM * 2);
  unsigned short* Wot      = (unsigned short*)alloc((size_t)NE * DIM * MDIM * 2);
  float* out_sorted = (float*)sorted_x;  // alias (see above)

  router_kernel<<<T_TOK / 16, 256, 0, stream>>>(x, wg, tok_eid, tok_w);
  plan_kernel<<<1, 256, 0, stream>>>(tok_eid, offsets, tstart, tok_slot);
  dispatch_kernel<<<T_TOK, 256, 0, stream>>>(x, tok_slot, sorted_x);
  // wi_0 [E][D][M] -> W0t [E][M][D]; wi_1 likewise; wo [E][M][D] -> Wot [E][D][M]
  transpose_cast_kernel<<<dim3(MDIM / 32, DIM / 32, NE), 256, 0, stream>>>(wi0, W0t, DIM, MDIM);
  transpose_cast_kernel<<<dim3(MDIM / 32, DIM / 32, NE), 256, 0, stream>>>(wi1, W1t, DIM, MDIM);
  transpose_cast_kernel<<<dim3(DIM / 32, MDIM / 32, NE), 256, 0, stream>>>(wo, Wot, MDIM, DIM);

  gemm12_kernel<<<dim3(MAXT, MDIM / 128, 1), 512, 131072, stream>>>(
      sorted_x, W0t, W1t, offsets, tstart, inter);
  gemm3_kernel<<<dim3(MAXT, DIM / 256, 1), 512, 131072, stream>>>(
      inter, Wot, offsets, tstart, out_sorted);
  combine_kernel<<<T_TOK / 4, 256, 0, stream>>>(out_sorted, tok_slot, tok_w, out);
}

// Round 6
// 590.346 us; speedup vs baseline: 1.1404x; 1.1047x over previous
//
#include <hip/hip_runtime.h>
#include <hip/hip_bf16.h>
#include <math.h>

// Problem dims (fixed by reference)
#define T_TOK 8192          // B*S tokens
#define DIM   2048          // D
#define NE    8             // experts
#define MDIM  1024          // intermediate
#define TK    16384         // T*K token copies
#define CAP   (TK + 256)    // slack rows so 256-row edge tiles can over-read safely

typedef __attribute__((ext_vector_type(8))) short bf16x8;
typedef __attribute__((ext_vector_type(4))) float f32x4;

typedef __attribute__((address_space(3))) unsigned char* lds_ptr_t;
typedef const __attribute__((address_space(1))) unsigned char* glb_ptr_t;

__device__ __forceinline__ unsigned short f2bf(float f) {
  union { float f; unsigned u; } v; v.f = f;
  unsigned r = v.u + 0x7fffu + ((v.u >> 16) & 1u);  // round-to-nearest-even
  return (unsigned short)(r >> 16);
}

__device__ __forceinline__ void gload_lds16(const void* g, void* l) {
  // each lane loads 16B from its own global addr; lands at lds_base + lane*16
  __builtin_amdgcn_global_load_lds((glb_ptr_t)g, (lds_ptr_t)l, 16, 0, 0);
}

#define VM_FENCE(n) asm volatile("s_waitcnt vmcnt(" #n ")" ::: "memory")
#define BARRIER() __builtin_amdgcn_s_barrier()

// Stage one 128x64 bf16 unit (16 KB) into LDS, linear dest, INVERSE-swizzled
// global source so that a swizzled ds_read (byte ^= (row&7)<<4) sees the right
// data (rule #21). 512 threads x 2 insts x 16B = 16 KB. 2 vmcnt incs per wave.
__device__ __forceinline__ void stage_unit(const unsigned short* __restrict__ src,
                                           int ld, unsigned char* lds, int tid) {
#pragma unroll
  for (int j = 0; j < 2; j++) {
    int idx = j * 512 + tid;
    int row = idx >> 3;                       // 0..127
    int gslot = (idx & 7) ^ (row & 7);        // inverse swizzle on source
    gload_lds16(src + (size_t)row * ld + gslot * 8, lds + ((idx & ~63) << 4));
  }
}

// 64-row unit (8 KB): 512 threads x 1 inst. Same swizzle.
__device__ __forceinline__ void stage_unit64(const unsigned short* __restrict__ src,
                                             int ld, unsigned char* lds, int tid) {
  int row = tid >> 3;                         // 0..63
  int gslot = (tid & 7) ^ (row & 7);
  gload_lds16(src + (size_t)row * ld + gslot * 8, lds + ((tid & ~63) << 4));
}

// Swizzled LDS fragment read: row stride 128B, XOR bits 4-6 with row&7.
// 16x16x32 frag pattern: 16-lane group spans 16 rows x 4 col-slots ->
// worst 2-way bank aliasing (free). (32x32 frags = structural 4-way, R3.)
__device__ __forceinline__ bf16x8 ldsfrag(const unsigned char* base, int row, int kb) {
  return *(const bf16x8*)(base + row * 128 + (kb ^ ((row & 7) << 4)));
}

// ---------------- router: fp64 logits, top-2, softmax weights ----------------
__global__ __launch_bounds__(256) void router_kernel(
    const float* __restrict__ x, const float* __restrict__ wg,
    int* __restrict__ tok_eid, float* __restrict__ tok_w) {
  __shared__ float wgT[NE][1024];  // 32 KB, one D-half at a time
  int tid = threadIdx.x;
  int wave = tid >> 6, lane = tid & 63;
  int t0 = blockIdx.x * 16 + wave * 4;  // 512 blocks x 4 waves x 4 tokens = 8192

  double acc[4][NE];
#pragma unroll
  for (int tt = 0; tt < 4; tt++)
#pragma unroll
    for (int e = 0; e < NE; e++) acc[tt][e] = 0.0;

  for (int p = 0; p < 2; p++) {
    __syncthreads();
#pragma unroll
    for (int j = tid; j < 2048; j += 256) {
      float4 v = ((const float4*)wg)[p * 2048 + j];
      int d = j >> 1, h = (j & 1) * 4;
      wgT[h + 0][d] = v.x;
      wgT[h + 1][d] = v.y;
      wgT[h + 2][d] = v.z;
      wgT[h + 3][d] = v.w;
    }
    __syncthreads();
#pragma unroll
    for (int it = 0; it < 4; it++) {
      int dd = it * 256 + lane * 4;
      int gd = p * 1024 + dd;
      float4 wf[NE];
#pragma unroll
      for (int e = 0; e < NE; e++) wf[e] = *(const float4*)&wgT[e][dd];
#pragma unroll
      for (int tt = 0; tt < 4; tt++) {
        float4 xv = *(const float4*)(x + (size_t)(t0 + tt) * DIM + gd);
#pragma unroll
        for (int e = 0; e < NE; e++) {
          acc[tt][e] += (double)xv.x * (double)wf[e].x;
          acc[tt][e] += (double)xv.y * (double)wf[e].y;
          acc[tt][e] += (double)xv.z * (double)wf[e].z;
          acc[tt][e] += (double)xv.w * (double)wf[e].w;
        }
      }
    }
  }
#pragma unroll
  for (int tt = 0; tt < 4; tt++)
#pragma unroll
    for (int e = 0; e < NE; e++) {
      double v = acc[tt][e];
#pragma unroll
      for (int off = 32; off > 0; off >>= 1) v += __shfl_down(v, off, 64);
      acc[tt][e] = v;
    }
  if (lane == 0) {
#pragma unroll
    for (int tt = 0; tt < 4; tt++) {
      int t = t0 + tt;
      int b0 = 0; double l0 = acc[tt][0];
#pragma unroll
      for (int e = 1; e < NE; e++) { if (acc[tt][e] > l0) { l0 = acc[tt][e]; b0 = e; } }
      int b1 = -1; double l1 = -1.0e300;
#pragma unroll
      for (int e = 0; e < NE; e++) { if (e != b0 && acc[tt][e] > l1) { l1 = acc[tt][e]; b1 = e; } }
      double w0 = 1.0 / (1.0 + exp(l1 - l0));
      tok_eid[2 * t]     = b0;
      tok_eid[2 * t + 1] = b1;
      tok_w[2 * t]     = (float)w0;
      tok_w[2 * t + 1] = (float)(1.0 - w0);
    }
  }
}

// ---------------- plan: counting sort of tok_eid -> offsets/tstart/tok_slot --
__global__ __launch_bounds__(256) void plan_kernel(
    const int* __restrict__ tok_eid, int* __restrict__ offsets,
    int* __restrict__ tstart, int* __restrict__ tok_slot) {
  __shared__ int cnt[256][NE];
  __shared__ int pre[256][NE];
  __shared__ int tot[NE];
  __shared__ int off_sh[NE + 1];
  int th = threadIdx.x;
  int c[NE];
#pragma unroll
  for (int k = 0; k < NE; k++) c[k] = 0;
  for (int i = 0; i < TK / 256; i++) {
    int e = tok_eid[i * 256 + th];
#pragma unroll
    for (int k = 0; k < NE; k++) c[k] += (e == k) ? 1 : 0;
  }
#pragma unroll
  for (int k = 0; k < NE; k++) cnt[th][k] = c[k];
  __syncthreads();
  if (th < NE) {
    int run = 0;
#pragma unroll 4
    for (int i = 0; i < 256; i++) { pre[i][th] = run; run += cnt[i][th]; }
    tot[th] = run;
  }
  __syncthreads();
  if (th == 0) {
    int s = 0, ts = 0;
    for (int e = 0; e < NE; e++) {
      off_sh[e] = s; offsets[e] = s; s += tot[e];
      tstart[e] = ts; ts += (tot[e] + 255) / 256;   // 256-row tiles
    }
    offsets[NE] = s; off_sh[NE] = s; tstart[NE] = ts;
  }
  __syncthreads();
  int b[NE];
#pragma unroll
  for (int k = 0; k < NE; k++) b[k] = off_sh[k] + pre[th][k];
  for (int i = 0; i < TK / 256; i++) {
    int idx = i * 256 + th;
    int e = tok_eid[idx];
    int slot = 0;
#pragma unroll
    for (int k = 0; k < NE; k++) {
      slot = (e == k) ? b[k] : slot;
      b[k] += (e == k) ? 1 : 0;
    }
    tok_slot[idx] = slot;
  }
}

// ---------------- dispatch: gather x -> sorted_x (bf16), atomic-free --------
__global__ __launch_bounds__(256) void dispatch_kernel(
    const float* __restrict__ x, const int* __restrict__ tok_slot,
    unsigned short* __restrict__ sorted_x) {
  int t = blockIdx.x;
  size_t s0 = (size_t)tok_slot[2 * t] * DIM;
  size_t s1 = (size_t)tok_slot[2 * t + 1] * DIM;
  const float4* xr = (const float4*)(x + (size_t)t * DIM);
#pragma unroll
  for (int i = threadIdx.x; i < DIM / 4; i += 256) {
    float4 v = xr[i];
    ushort4 b;
    b.x = f2bf(v.x); b.y = f2bf(v.y); b.z = f2bf(v.z); b.w = f2bf(v.w);
    *(ushort4*)(sorted_x + s0 + (size_t)i * 4) = b;
    *(ushort4*)(sorted_x + s1 + (size_t)i * 4) = b;
  }
}

// ---------------- weight cast + transpose: f32 [R][C] -> bf16 [C][R] --------
__global__ __launch_bounds__(256) void transpose_cast_kernel(
    const float* __restrict__ in, unsigned short* __restrict__ out, int R, int C) {
  __shared__ unsigned short tile[32][33];
  int e = blockIdx.z;
  const float* inp = in + (size_t)e * R * C;
  unsigned short* outp = out + (size_t)e * R * C;
  int c0 = blockIdx.x * 32, r0 = blockIdx.y * 32;
  int tx = threadIdx.x & 31, ty = threadIdx.x >> 5;
#pragma unroll
  for (int i = 0; i < 32; i += 8)
    tile[ty + i][tx] = f2bf(inp[(size_t)(r0 + ty + i) * C + (c0 + tx)]);
  __syncthreads();
#pragma unroll
  for (int i = 0; i < 32; i += 8)
    outp[(size_t)(c0 + ty + i) * R + (r0 + tx)] = tile[tx][ty + i];
}

// ---------------- GEMM12: inter = silu(A@wi0) * (A@wi1) --------------------
// PERFECT-PACKING GRID: T = sum_e ceil(cnt_e/256) >= 64 always, so the first
// 64 row-tiles x 8 col-blocks = 512 flat tiles are ALWAYS valid -> exactly
// 2 full dispatch rounds on 256 CUs (1 block/CU at 128 KiB LDS). Overflow
// row-tiles 64..T-1 (<=8) run as 4x row-quarters (<=256 short blocks, ~1
// round). Main body = R2's verified 4-phase schedule, byte-identical.
__global__ __launch_bounds__(512, 2) void gemm12_kernel(
    const unsigned short* __restrict__ A, const unsigned short* __restrict__ W0t,
    const unsigned short* __restrict__ W1t, const int* __restrict__ offsets,
    const int* __restrict__ tstart, unsigned short* __restrict__ inter) {
  extern __shared__ unsigned char smem[];
  int bx = blockIdx.x;
  int tid = threadIdx.x;
  int wave = tid >> 6, lane = tid & 63;
  int wm = wave >> 2, wn = wave & 3;
  int l15 = lane & 15, grp16 = (lane >> 4) * 16;

  if (bx < 512) {
    // ================= main path: full 256x128 tile, 4-phase =================
    int rt = bx >> 3;                 // 0..63, always < T
    int colb = (bx & 7) * 128;
    int e = 0;
#pragma unroll
    for (int k = 1; k < NE; k++) if (tstart[k] <= rt) e = k;
    int row_end = offsets[e + 1];
    int tile_r0 = offsets[e] + (rt - tstart[e]) * 256;

    const unsigned short* Ab = A + (size_t)tile_r0 * DIM;
    const unsigned short* B0b = W0t + ((size_t)e * MDIM + colb) * DIM;
    const unsigned short* B1b = W1t + ((size_t)e * MDIM + colb) * DIM;

    f32x4 acc0[8][2], acc1[8][2];   // [half*4+mi][ni]
#pragma unroll
    for (int i = 0; i < 8; i++)
#pragma unroll
      for (int j = 0; j < 2; j++) {
        acc0[i][j] = (f32x4){0.f, 0.f, 0.f, 0.f};
        acc1[i][j] = (f32x4){0.f, 0.f, 0.f, 0.f};
      }
    bf16x8 af[4][2], b0f[2][2], b1f[2][2];

    // prologue: tile 0 -> buf0, issue order A0,B0,B1,A1
    stage_unit(Ab, DIM, smem + 0, tid);
    stage_unit(B0b, DIM, smem + 32768, tid);
    stage_unit(B1b, DIM, smem + 49152, tid);
    stage_unit(Ab + (size_t)128 * DIM, DIM, smem + 16384, tid);
    VM_FENCE(4);   // A0,B0 landed; B1,A1 in flight
    BARRIER();

    for (int t = 0; t < 32; t++) {
      unsigned char* S = smem + (t & 1) * 65536;
      unsigned char* P = smem + ((t & 1) ^ 1) * 65536;
      int kn = (t < 31 ? t + 1 : t) * 64;   // clamp keeps vmcnt counts uniform
      // ---- p0: read A half0 + B0 frags; stage next A0; MFMA W0 x half0
#pragma unroll
      for (int mi = 0; mi < 4; mi++) {
        int r = wm * 64 + mi * 16 + l15;              // rows 0..127 = unit A0
#pragma unroll
        for (int ks = 0; ks < 2; ks++) af[mi][ks] = ldsfrag(S, r, ks * 64 + grp16);
      }
#pragma unroll
      for (int ni = 0; ni < 2; ni++) {
        int r = wn * 32 + ni * 16 + l15;              // rows 0..127 = unit B0
#pragma unroll
        for (int ks = 0; ks < 2; ks++) b0f[ni][ks] = ldsfrag(S + 32768, r, ks * 64 + grp16);
      }
      stage_unit(Ab + kn, DIM, P, tid);
      BARRIER();
      __builtin_amdgcn_s_setprio(1);
#pragma unroll
      for (int ks = 0; ks < 2; ks++)
#pragma unroll
        for (int mi = 0; mi < 4; mi++)
#pragma unroll
          for (int ni = 0; ni < 2; ni++)
            acc0[mi][ni] = __builtin_amdgcn_mfma_f32_16x16x32_bf16(af[mi][ks], b0f[ni][ks], acc0[mi][ni], 0, 0, 0);
      __builtin_amdgcn_s_setprio(0);
      VM_FENCE(4);   // cur B1 landed (read at p1 start)
      BARRIER();
      // ---- p1: read B1 frags; stage next B0; MFMA W1 x half0
#pragma unroll
      for (int ni = 0; ni < 2; ni++) {
        int r = wn * 32 + ni * 16 + l15;              // rows 0..127 = unit B1
#pragma unroll
        for (int ks = 0; ks < 2; ks++) b1f[ni][ks] = ldsfrag(S + 49152, r, ks * 64 + grp16);
      }
      stage_unit(B0b + kn, DIM, P + 32768, tid);
      BARRIER();
      __builtin_amdgcn_s_setprio(1);
#pragma unroll
      for (int ks = 0; ks < 2; ks++)
#pragma unroll
        for (int mi = 0; mi < 4; mi++)
#pragma unroll
          for (int ni = 0; ni < 2; ni++)
            acc1[mi][ni] = __builtin_amdgcn_mfma_f32_16x16x32_bf16(af[mi][ks], b1f[ni][ks], acc1[mi][ni], 0, 0, 0);
      __builtin_amdgcn_s_setprio(0);
      VM_FENCE(4);   // cur A1 landed (read at p2 start)
      BARRIER();
      // ---- p2: read A half1 frags; stage next B1; MFMA W0 x half1 (b0f reused)
#pragma unroll
      for (int mi = 0; mi < 4; mi++) {
        int r = 128 + wm * 64 + mi * 16 + l15;        // rows 128..255 = unit A1
#pragma unroll
        for (int ks = 0; ks < 2; ks++) af[mi][ks] = ldsfrag(S, r, ks * 64 + grp16);
      }
      stage_unit(B1b + kn, DIM, P + 49152, tid);
      BARRIER();
      __builtin_amdgcn_s_setprio(1);
#pragma unroll
      for (int ks = 0; ks < 2; ks++)
#pragma unroll
        for (int mi = 0; mi < 4; mi++)
#pragma unroll
          for (int ni = 0; ni < 2; ni++)
            acc0[4 + mi][ni] = __builtin_amdgcn_mfma_f32_16x16x32_bf16(af[mi][ks], b0f[ni][ks], acc0[4 + mi][ni], 0, 0, 0);
      __builtin_amdgcn_s_setprio(0);
      BARRIER();
      // ---- p3: stage next A1; MFMA W1 x half1 (af, b1f reused)
      stage_unit(Ab + (size_t)128 * DIM + kn, DIM, P + 16384, tid);
      BARRIER();
      __builtin_amdgcn_s_setprio(1);
#pragma unroll
      for (int ks = 0; ks < 2; ks++)
#pragma unroll
        for (int mi = 0; mi < 4; mi++)
#pragma unroll
          for (int ni = 0; ni < 2; ni++)
            acc1[4 + mi][ni] = __builtin_amdgcn_mfma_f32_16x16x32_bf16(af[mi][ks], b1f[ni][ks], acc1[4 + mi][ni], 0, 0, 0);
      __builtin_amdgcn_s_setprio(0);
      VM_FENCE(4);   // next A0,B0 landed; next B1,A1 stay in flight
      BARRIER();
    }
    VM_FENCE(0);  // drain clamped last-iter stages

    // epilogue: silu(h0)*h1 -> inter (bf16)
#pragma unroll
    for (int half = 0; half < 2; half++)
#pragma unroll
      for (int mi = 0; mi < 4; mi++)
#pragma unroll
        for (int reg = 0; reg < 4; reg++) {
          int grow = tile_r0 + half * 128 + wm * 64 + mi * 16 + (lane >> 4) * 4 + reg;
          if (grow < row_end) {
#pragma unroll
            for (int ni = 0; ni < 2; ni++) {
              float h0 = acc0[half * 4 + mi][ni][reg];
              float h1 = acc1[half * 4 + mi][ni][reg];
              float g = h0 / (1.0f + __expf(-h0));
              inter[(size_t)grow * MDIM + colb + wn * 32 + ni * 16 + l15] = f2bf(g * h1);
            }
          }
        }
  } else {
    // ========== tail path: 64-row quarter of overflow tile, 2-phase ==========
    int g = bx - 512;
    int rt = 64 + (g >> 5);           // overflow row-tile
    if (rt >= tstart[NE]) return;
    int q = (g >> 3) & 3;
    int colb = (g & 7) * 128;
    int e = 0;
#pragma unroll
    for (int k = 1; k < NE; k++) if (tstart[k] <= rt) e = k;
    int row_end = offsets[e + 1];
    int tr0 = offsets[e] + (rt - tstart[e]) * 256 + q * 64;
    if (tr0 >= row_end) return;

    const unsigned short* Ab = A + (size_t)tr0 * DIM;
    const unsigned short* B0b = W0t + ((size_t)e * MDIM + colb) * DIM;
    const unsigned short* B1b = W1t + ((size_t)e * MDIM + colb) * DIM;

    // waves: wm (0/1) -> 32-row slice; wn -> 32-col slice
    f32x4 acc0[2][2], acc1[2][2];
#pragma unroll
    for (int i = 0; i < 2; i++)
#pragma unroll
      for (int j = 0; j < 2; j++) {
        acc0[i][j] = (f32x4){0.f, 0.f, 0.f, 0.f};
        acc1[i][j] = (f32x4){0.f, 0.f, 0.f, 0.f};
      }
    bf16x8 af[2][2], b0f[2][2], b1f[2][2];

    // LDS per buf: Aq @+0 (8K), B0 @+16384 (16K), B1 @+49152 (16K)
    stage_unit64(Ab, DIM, smem + 0, tid);
    stage_unit(B0b, DIM, smem + 16384, tid);
    stage_unit(B1b, DIM, smem + 49152, tid);
    VM_FENCE(0);
    BARRIER();

    for (int t = 0; t < 32; t++) {
      unsigned char* S = smem + (t & 1) * 65536;
      unsigned char* P = smem + ((t & 1) ^ 1) * 65536;
      int kn = (t < 31 ? t + 1 : t) * 64;
      stage_unit64(Ab + kn, DIM, P, tid);
      stage_unit(B0b + kn, DIM, P + 16384, tid);
      stage_unit(B1b + kn, DIM, P + 49152, tid);
#pragma unroll
      for (int mi = 0; mi < 2; mi++) {
        int r = wm * 32 + mi * 16 + l15;            // rows 0..63
#pragma unroll
        for (int ks = 0; ks < 2; ks++) af[mi][ks] = ldsfrag(S, r, ks * 64 + grp16);
      }
#pragma unroll
      for (int ni = 0; ni < 2; ni++) {
        int r = wn * 32 + ni * 16 + l15;            // rows 0..127
#pragma unroll
        for (int ks = 0; ks < 2; ks++) {
          b0f[ni][ks] = ldsfrag(S + 16384, r, ks * 64 + grp16);
          b1f[ni][ks] = ldsfrag(S + 49152, r, ks * 64 + grp16);
        }
      }
      __builtin_amdgcn_s_setprio(1);
#pragma unroll
      for (int ks = 0; ks < 2; ks++)
#pragma unroll
        for (int mi = 0; mi < 2; mi++)
#pragma unroll
          for (int ni = 0; ni < 2; ni++) {
            acc0[mi][ni] = __builtin_amdgcn_mfma_f32_16x16x32_bf16(af[mi][ks], b0f[ni][ks], acc0[mi][ni], 0, 0, 0);
            acc1[mi][ni] = __builtin_amdgcn_mfma_f32_16x16x32_bf16(af[mi][ks], b1f[ni][ks], acc1[mi][ni], 0, 0, 0);
          }
      __builtin_amdgcn_s_setprio(0);
      VM_FENCE(0);
      BARRIER();
    }

#pragma unroll
    for (int mi = 0; mi < 2; mi++)
#pragma unroll
      for (int reg = 0; reg < 4; reg++) {
        int grow = tr0 + wm * 32 + mi * 16 + (lane >> 4) * 4 + reg;
        if (grow < row_end) {
#pragma unroll
          for (int ni = 0; ni < 2; ni++) {
            float h0 = acc0[mi][ni][reg];
            float h1 = acc1[mi][ni][reg];
            float gq = h0 / (1.0f + __expf(-h0));
            inter[(size_t)grow * MDIM + colb + wn * 32 + ni * 16 + l15] = f2bf(gq * h1);
          }
        }
      }
  }
}

// ---------------- GEMM3: out_sorted = inter @ wo ---------------------------
// Same perfect-packing grid: 512 always-valid main tiles (256x256, 4-phase,
// R2 body) + <=256 tail quarter blocks (64x256, 2-phase).
__global__ __launch_bounds__(512, 2) void gemm3_kernel(
    const unsigned short* __restrict__ A, const unsigned short* __restrict__ Wot,
    const int* __restrict__ offsets, const int* __restrict__ tstart,
    float* __restrict__ out_sorted) {
  extern __shared__ unsigned char smem[];
  int bx = blockIdx.x;
  int tid = threadIdx.x;
  int wave = tid >> 6, lane = tid & 63;
  int wm = wave >> 2, wn = wave & 3;
  int l15 = lane & 15, grp16 = (lane >> 4) * 16;

  if (bx < 512) {
    // ================= main path =================
    int rt = bx >> 3;
    int col0 = (bx & 7) * 256;
    int e = 0;
#pragma unroll
    for (int k = 1; k < NE; k++) if (tstart[k] <= rt) e = k;
    int row_end = offsets[e + 1];
    int tile_r0 = offsets[e] + (rt - tstart[e]) * 256;

    const unsigned short* Ab = A + (size_t)tile_r0 * MDIM;
    const unsigned short* Bb = Wot + ((size_t)e * DIM + col0) * MDIM;

    f32x4 acc[8][4];   // [mh*4+mi][nh*2+ni]
#pragma unroll
    for (int i = 0; i < 8; i++)
#pragma unroll
      for (int j = 0; j < 4; j++) acc[i][j] = (f32x4){0.f, 0.f, 0.f, 0.f};
    bf16x8 af[4][2], bfr[4][2];

    stage_unit(Ab, MDIM, smem + 0, tid);
    stage_unit(Bb, MDIM, smem + 32768, tid);
    stage_unit(Bb + (size_t)128 * MDIM, MDIM, smem + 49152, tid);
    stage_unit(Ab + (size_t)128 * MDIM, MDIM, smem + 16384, tid);
    VM_FENCE(4);
    BARRIER();

    for (int t = 0; t < 16; t++) {
      unsigned char* S = smem + (t & 1) * 65536;
      unsigned char* P = smem + ((t & 1) ^ 1) * 65536;
      int kn = (t < 15 ? t + 1 : t) * 64;
      // ---- p0
#pragma unroll
      for (int mi = 0; mi < 4; mi++) {
        int r = wm * 64 + mi * 16 + l15;              // unit A0
#pragma unroll
        for (int ks = 0; ks < 2; ks++) af[mi][ks] = ldsfrag(S, r, ks * 64 + grp16);
      }
#pragma unroll
      for (int ni = 0; ni < 2; ni++) {
        int r = wn * 32 + ni * 16 + l15;              // unit B0
#pragma unroll
        for (int ks = 0; ks < 2; ks++) bfr[ni][ks] = ldsfrag(S + 32768, r, ks * 64 + grp16);
      }
      stage_unit(Ab + kn, MDIM, P, tid);
      BARRIER();
      __builtin_amdgcn_s_setprio(1);
#pragma unroll
      for (int ks = 0; ks < 2; ks++)
#pragma unroll
        for (int mi = 0; mi < 4; mi++)
#pragma unroll
          for (int ni = 0; ni < 2; ni++)
            acc[mi][ni] = __builtin_amdgcn_mfma_f32_16x16x32_bf16(af[mi][ks], bfr[ni][ks], acc[mi][ni], 0, 0, 0);
      __builtin_amdgcn_s_setprio(0);
      VM_FENCE(4);   // cur B1 landed
      BARRIER();
      // ---- p1
#pragma unroll
      for (int ni = 0; ni < 2; ni++) {
        int r = 128 + wn * 32 + ni * 16 + l15;        // unit B1
#pragma unroll
        for (int ks = 0; ks < 2; ks++) bfr[2 + ni][ks] = ldsfrag(S + 32768, r, ks * 64 + grp16);
      }
      stage_unit(Bb + kn, MDIM, P + 32768, tid);
      BARRIER();
      __builtin_amdgcn_s_setprio(1);
#pragma unroll
      for (int ks = 0; ks < 2; ks++)
#pragma unroll
        for (int mi = 0; mi < 4; mi++)
#pragma unroll
          for (int ni = 0; ni < 2; ni++)
            acc[mi][2 + ni] = __builtin_amdgcn_mfma_f32_16x16x32_bf16(af[mi][ks], bfr[2 + ni][ks], acc[mi][2 + ni], 0, 0, 0);
      __builtin_amdgcn_s_setprio(0);
      VM_FENCE(4);   // cur A1 landed
      BARRIER();
      // ---- p2
#pragma unroll
      for (int mi = 0; mi < 4; mi++) {
        int r = 128 + wm * 64 + mi * 16 + l15;        // unit A1
#pragma unroll
        for (int ks = 0; ks < 2; ks++) af[mi][ks] = ldsfrag(S, r, ks * 64 + grp16);
      }
      stage_unit(Bb + (size_t)128 * MDIM + kn, MDIM, P + 49152, tid);
      BARRIER();
      __builtin_amdgcn_s_setprio(1);
#pragma unroll
      for (int ks = 0; ks < 2; ks++)
#pragma unroll
        for (int mi = 0; mi < 4; mi++)
#pragma unroll
          for (int ni = 0; ni < 2; ni++)
            acc[4 + mi][ni] = __builtin_amdgcn_mfma_f32_16x16x32_bf16(af[mi][ks], bfr[ni][ks], acc[4 + mi][ni], 0, 0, 0);
      __builtin_amdgcn_s_setprio(0);
      BARRIER();
      // ---- p3
      stage_unit(Ab + (size_t)128 * MDIM + kn, MDIM, P + 16384, tid);
      BARRIER();
      __builtin_amdgcn_s_setprio(1);
#pragma unroll
      for (int ks = 0; ks < 2; ks++)
#pragma unroll
        for (int mi = 0; mi < 4; mi++)
#pragma unroll
          for (int ni = 0; ni < 2; ni++)
            acc[4 + mi][2 + ni] = __builtin_amdgcn_mfma_f32_16x16x32_bf16(af[mi][ks], bfr[2 + ni][ks], acc[4 + mi][2 + ni], 0, 0, 0);
      __builtin_amdgcn_s_setprio(0);
      VM_FENCE(4);   // next A0,B0 landed
      BARRIER();
    }
    VM_FENCE(0);

#pragma unroll
    for (int mh = 0; mh < 2; mh++)
#pragma unroll
      for (int mi = 0; mi < 4; mi++)
#pragma unroll
        for (int reg = 0; reg < 4; reg++) {
          int grow = tile_r0 + mh * 128 + wm * 64 + mi * 16 + (lane >> 4) * 4 + reg;
          if (grow < row_end) {
#pragma unroll
            for (int nh = 0; nh < 2; nh++) {
              float* orow = out_sorted + (size_t)grow * DIM + col0 + nh * 128 + wn * 32 + l15;
#pragma unroll
              for (int ni = 0; ni < 2; ni++)
                orow[ni * 16] = acc[mh * 4 + mi][nh * 2 + ni][reg];
            }
          }
        }
  } else {
    // ========== tail path: 64 rows x 256 cols, 2-phase ==========
    int g = bx - 512;
    int rt = 64 + (g >> 5);
    if (rt >= tstart[NE]) return;
    int q = (g >> 3) & 3;
    int col0 = (g & 7) * 256;
    int e = 0;
#pragma unroll
    for (int k = 1; k < NE; k++) if (tstart[k] <= rt) e = k;
    int row_end = offsets[e + 1];
    int tr0 = offsets[e] + (rt - tstart[e]) * 256 + q * 64;
    if (tr0 >= row_end) return;

    const unsigned short* Ab = A + (size_t)tr0 * MDIM;
    const unsigned short* Bb = Wot + ((size_t)e * DIM + col0) * MDIM;

    // waves: wm (0/1) -> 32-row slice; wn -> 64-col slice
    f32x4 acc[2][4];
#pragma unroll
    for (int i = 0; i < 2; i++)
#pragma unroll
      for (int j = 0; j < 4; j++) acc[i][j] = (f32x4){0.f, 0.f, 0.f, 0.f};
    bf16x8 af[2][2], bfr[4][2];

    // LDS per buf: Aq @+0 (8K), B0 @+16384 (16K, cols 0..127), B1 @+49152
    stage_unit64(Ab, MDIM, smem + 0, tid);
    stage_unit(Bb, MDIM, smem + 16384, tid);
    stage_unit(Bb + (size_t)128 * MDIM, MDIM, smem + 49152, tid);
    VM_FENCE(0);
    BARRIER();

    for (int t = 0; t < 16; t++) {
      unsigned char* S = smem + (t & 1) * 65536;
      unsigned char* P = smem + ((t & 1) ^ 1) * 65536;
      int kn = (t < 15 ? t + 1 : t) * 64;
      stage_unit64(Ab + kn, MDIM, P, tid);
      stage_unit(Bb + kn, MDIM, P + 16384, tid);
      stage_unit(Bb + (size_t)128 * MDIM + kn, MDIM, P + 49152, tid);
#pragma unroll
      for (int mi = 0; mi < 2; mi++) {
        int r = wm * 32 + mi * 16 + l15;            // rows 0..63
#pragma unroll
        for (int ks = 0; ks < 2; ks++) af[mi][ks] = ldsfrag(S, r, ks * 64 + grp16);
      }
#pragma unroll
      for (int ni = 0; ni < 4; ni++) {
        int r = wn * 64 + ni * 16 + l15;            // 0..255 across two units
        const unsigned char* Bbase = (r < 128) ? (S + 16384) : (S + 32768);
#pragma unroll
        for (int ks = 0; ks < 2; ks++) bfr[ni][ks] = ldsfrag(Bbase, r, ks * 64 + grp16);
      }
      __builtin_amdgcn_s_setprio(1);
#pragma unroll
      for (int ks = 0; ks < 2; ks++)
#pragma unroll
        for (int mi = 0; mi < 2; mi++)
#pragma unroll
          for (int ni = 0; ni < 4; ni++)
            acc[mi][ni] = __builtin_amdgcn_mfma_f32_16x16x32_bf16(af[mi][ks], bfr[ni][ks], acc[mi][ni], 0, 0, 0);
      __builtin_amdgcn_s_setprio(0);
      VM_FENCE(0);
      BARRIER();
    }

#pragma unroll
    for (int mi = 0; mi < 2; mi++)
#pragma unroll
      for (int reg = 0; reg < 4; reg++) {
        int grow = tr0 + wm * 32 + mi * 16 + (lane >> 4) * 4 + reg;
        if (grow < row_end) {
          float* orow = out_sorted + (size_t)grow * DIM + col0 + wn * 64 + l15;
#pragma unroll
          for (int ni = 0; ni < 4; ni++)
            orow[ni * 16] = acc[mi][ni][reg];
        }
      }
  }
}

// ---------------- combine: out[t] = w0*os[slot0] + w1*os[slot1] -------------
__global__ __launch_bounds__(256) void combine_kernel(
    const float* __restrict__ os, const int* __restrict__ tok_slot,
    const float* __restrict__ tok_w, float* __restrict__ out) {
  int t = blockIdx.x * 4 + (threadIdx.x >> 6);
  int lane = threadIdx.x & 63;
  int s0 = tok_slot[2 * t], s1 = tok_slot[2 * t + 1];
  float w0 = tok_w[2 * t], w1 = tok_w[2 * t + 1];
  const float4* a = (const float4*)(os + (size_t)s0 * DIM);
  const float4* b = (const float4*)(os + (size_t)s1 * DIM);
  float4* o = (float4*)(out + (size_t)t * DIM);
#pragma unroll
  for (int i = lane; i < DIM / 4; i += 64) {
    float4 va = a[i], vb = b[i];
    float4 r;
    r.x = w0 * va.x + w1 * vb.x;
    r.y = w0 * va.y + w1 * vb.y;
    r.z = w0 * va.z + w1 * vb.z;
    r.w = w0 * va.w + w1 * vb.w;
    o[i] = r;
  }
}

// ---------------------------------------------------------------------------
extern "C" void kernel_launch(void* const* d_in, const int* in_sizes, int n_in,
                              void* d_out, int out_size, void* d_ws, size_t ws_size,
                              hipStream_t stream) {
  const float* x   = (const float*)d_in[0];
  const float* wg  = (const float*)d_in[1];
  const float* wi0 = (const float*)d_in[2];
  const float* wi1 = (const float*)d_in[3];
  const float* wo  = (const float*)d_in[4];
  float* out = (float*)d_out;

  // opt-in to 128 KiB dynamic LDS (call unconditionally; cheap host-side op)
  (void)hipFuncSetAttribute(reinterpret_cast<const void*>(gemm12_kernel),
                            hipFuncAttributeMaxDynamicSharedMemorySize, 131072);
  (void)hipFuncSetAttribute(reinterpret_cast<const void*>(gemm3_kernel),
                            hipFuncAttributeMaxDynamicSharedMemorySize, 131072);

  char* ws = (char*)d_ws;
  size_t off = 0;
  auto alloc = [&](size_t bytes) -> void* {
    void* p = ws + off;
    off = (off + bytes + 255) & ~(size_t)255;
    return p;
  };
  int*   offsets  = (int*)alloc((NE + 1) * 4);
  int*   tstart   = (int*)alloc((NE + 1) * 4);
  int*   tok_eid  = (int*)alloc((size_t)2 * T_TOK * 4);
  float* tok_w    = (float*)alloc((size_t)2 * T_TOK * 4);
  int*   tok_slot = (int*)alloc((size_t)2 * T_TOK * 4);
  unsigned short* inter    = (unsigned short*)alloc((size_t)CAP * MDIM * 2);
  // sorted_x + W0t + W1t form one contiguous 135.3 MB window; after gemm12
  // they are dead and out_sorted (16384*DIM*4 = 134.22 MB) aliases the window.
  unsigned short* sorted_x = (unsigned short*)alloc((size_t)CAP * DIM * 2);
  unsigned short* W0t      = (unsigned short*)alloc((size_t)NE * MDIM * DIM * 2);
  unsigned short* W1t      = (unsigned short*)alloc((size_t)NE * MDIM * DIM * 2);
  unsigned short* Wot      = (unsigned short*)alloc((size_t)NE * DIM * MDIM * 2);
  float* out_sorted = (float*)sorted_x;  // alias (see above)

  router_kernel<<<T_TOK / 16, 256, 0, stream>>>(x, wg, tok_eid, tok_w);
  plan_kernel<<<1, 256, 0, stream>>>(tok_eid, offsets, tstart, tok_slot);
  dispatch_kernel<<<T_TOK, 256, 0, stream>>>(x, tok_slot, sorted_x);
  // wi_0 [E][D][M] -> W0t [E][M][D]; wi_1 likewise; wo [E][M][D] -> Wot [E][D][M]
  transpose_cast_kernel<<<dim3(MDIM / 32, DIM / 32, NE), 256, 0, stream>>>(wi0, W0t, DIM, MDIM);
  transpose_cast_kernel<<<dim3(MDIM / 32, DIM / 32, NE), 256, 0, stream>>>(wi1, W1t, DIM, MDIM);
  transpose_cast_kernel<<<dim3(DIM / 32, MDIM / 32, NE), 256, 0, stream>>>(wo, Wot, MDIM, DIM);

  // perfect-packing grids: 512 always-valid main tiles + 256 tail quarters
  gemm12_kernel<<<dim3(768, 1, 1), 512, 131072, stream>>>(
      sorted_x, W0t, W1t, offsets, tstart, inter);
  gemm3_kernel<<<dim3(768, 1, 1), 512, 131072, stream>>>(
      inter, Wot, offsets, tstart, out_sorted);
  combine_kernel<<<T_TOK / 4, 256, 0, stream>>>(out_sorted, tok_slot, tok_w, out);
}